// Round 1
// baseline (413.663 us; speedup 1.0000x reference)
//
#include <hip/hip_runtime.h>

// ---------------------------------------------------------------------------
// Local windowed attention, B=8 N=8192 D=512, WS=128, lookback=1.
//   k_qkv : Q/K/V projections fp32->bf16 MFMA GEMM. Q,K row-major bf16;
//           V stored transposed Vt[b][d][n] for contiguous PV B-fragments.
//   k_attn: per (b,window): S=QK^T (K staged in swizzled LDS, Q direct),
//           masked block softmax (cross-wave via LDS partials),
//           O=PV (P bf16 in swizzled LDS, V direct from Vt).
// ---------------------------------------------------------------------------

typedef __bf16 bf16x8 __attribute__((ext_vector_type(8)));
typedef float f32x4 __attribute__((ext_vector_type(4)));
typedef unsigned short u16x8 __attribute__((ext_vector_type(8)));

#define BATCH 8
#define SEQ   8192
#define DIM   512
#define NWIN  64
#define TOKS  (BATCH * SEQ)          // 65536
#define WSELEM ((size_t)TOKS * DIM)  // 33554432 elements per Q/K/V buffer

__device__ __forceinline__ unsigned short f2b(float f) {
    union { float f; unsigned int u; } c; c.f = f;
    unsigned int u = c.u;
    return (unsigned short)((u + 0x7FFFu + ((u >> 16) & 1u)) >> 16);
}

// XOR swizzle for [rows][64]-ushort LDS tiles (128B rows): spread 8 rows
// across the 8 16B slots of a 128B line. idx/col in ushort units, col%8==0.
__device__ __forceinline__ int swz64(int row, int col) {
    return (row * 64 + col) ^ ((row & 7) << 3);
}

// ===========================================================================
// Kernel 1: fused QKV projection GEMM.  grid = 3 * (TOKS/128) * (DIM/128)
// block = 256 (4 waves, 2x2 wave grid, wave tile 64x64, BK=64)
// ===========================================================================
__global__ __launch_bounds__(256) void k_qkv(
    const float* __restrict__ x,
    const float* __restrict__ wq, const float* __restrict__ bq,
    const float* __restrict__ wk, const float* __restrict__ bk,
    const float* __restrict__ wv, const float* __restrict__ bv,
    unsigned short* __restrict__ qo, unsigned short* __restrict__ ko,
    unsigned short* __restrict__ vto)
{
    __shared__ __align__(16) unsigned short sm[16512]; // Xs[0:8192)|Ws[8192:16384); V-epilogue T[128][129] aliases
    unsigned short* Xs = sm;
    unsigned short* Ws = sm + 8192;

    const int bid  = blockIdx.x;
    const int wsel = bid >> 11;          // 0=Q 1=K 2=V (2048 blocks each)
    const int rem  = bid & 2047;
    const int mt = rem >> 2, nt = rem & 3;
    const int rbase = mt << 7;           // token row base (0..65535)
    const int cbase = nt << 7;           // output feature base (0..511)

    const float* __restrict__ w    = (wsel == 0) ? wq : (wsel == 1) ? wk : wv;
    const float* __restrict__ bias = (wsel == 0) ? bq : (wsel == 1) ? bk : bv;

    const int tid  = threadIdx.x;
    const int lane = tid & 63;
    const int wid  = tid >> 6;
    const int wm = wid >> 1, wn = wid & 1;
    const int l15 = lane & 15, lg = lane >> 4;

    f32x4 acc[4][4];
#pragma unroll
    for (int m = 0; m < 4; ++m)
#pragma unroll
        for (int n = 0; n < 4; ++n) acc[m][n] = (f32x4){0.f, 0.f, 0.f, 0.f};

    const int srow = tid >> 3;          // 0..31
    const int sc8  = (tid & 7) << 3;    // ushort col, multiple of 8

    for (int ks = 0; ks < 8; ++ks) {
        const int kc = ks << 6;
        // ---- stage X and W chunks (f32 -> bf16) into swizzled LDS
#pragma unroll
        for (int p = 0; p < 4; ++p) {
            const int row = (p << 5) + srow;
            const float* xs = x + (size_t)(rbase + row) * DIM + kc + sc8;
            float4 f0 = *(const float4*)xs;
            float4 f1 = *(const float4*)(xs + 4);
            u16x8 v;
            v[0] = f2b(f0.x); v[1] = f2b(f0.y); v[2] = f2b(f0.z); v[3] = f2b(f0.w);
            v[4] = f2b(f1.x); v[5] = f2b(f1.y); v[6] = f2b(f1.z); v[7] = f2b(f1.w);
            *(u16x8*)&Xs[swz64(row, sc8)] = v;
            const float* wsp = w + (size_t)(cbase + row) * DIM + kc + sc8;
            float4 g0 = *(const float4*)wsp;
            float4 g1 = *(const float4*)(wsp + 4);
            u16x8 v2;
            v2[0] = f2b(g0.x); v2[1] = f2b(g0.y); v2[2] = f2b(g0.z); v2[3] = f2b(g0.w);
            v2[4] = f2b(g1.x); v2[5] = f2b(g1.y); v2[6] = f2b(g1.z); v2[7] = f2b(g1.w);
            *(u16x8*)&Ws[swz64(row, sc8)] = v2;
        }
        __syncthreads();
        // ---- MFMA on the 64-wide K chunk
#pragma unroll
        for (int kk = 0; kk < 64; kk += 32) {
            const int cu = kk + (lg << 3);
            bf16x8 af[4], bf[4];
#pragma unroll
            for (int m = 0; m < 4; ++m) {
                const int r = (wm << 6) + (m << 4) + l15;
                af[m] = *(const bf16x8*)&Xs[swz64(r, cu)];
            }
#pragma unroll
            for (int n = 0; n < 4; ++n) {
                const int r = (wn << 6) + (n << 4) + l15;
                bf[n] = *(const bf16x8*)&Ws[swz64(r, cu)];
            }
#pragma unroll
            for (int m = 0; m < 4; ++m)
#pragma unroll
                for (int n = 0; n < 4; ++n)
                    acc[m][n] = __builtin_amdgcn_mfma_f32_16x16x32_bf16(
                        af[m], bf[n], acc[m][n], 0, 0, 0);
        }
        __syncthreads();
    }

    if (wsel < 2) {
        // ---- Q/K epilogue: row-major bf16 store
        unsigned short* __restrict__ out = wsel ? ko : qo;
#pragma unroll
        for (int n = 0; n < 4; ++n) {
            const int col = cbase + (wn << 6) + (n << 4) + l15;
            const float bv_ = bias[col];
#pragma unroll
            for (int m = 0; m < 4; ++m)
#pragma unroll
                for (int j = 0; j < 4; ++j) {
                    const int row = rbase + (wm << 6) + (m << 4) + (lg << 2) + j;
                    out[(size_t)row * DIM + col] = f2b(acc[m][n][j] + bv_);
                }
        }
    } else {
        // ---- V epilogue: transpose via LDS T[128][129], store Vt[b][d][n]
#pragma unroll
        for (int n = 0; n < 4; ++n) {
            const int dv = (wn << 6) + (n << 4) + l15;
            const float bv_ = bias[cbase + dv];
#pragma unroll
            for (int m = 0; m < 4; ++m)
#pragma unroll
                for (int j = 0; j < 4; ++j) {
                    const int tok = (wm << 6) + (m << 4) + (lg << 2) + j;
                    sm[tok * 129 + dv] = f2b(acc[m][n][j] + bv_);
                }
        }
        __syncthreads();
        const int batch = rbase >> 13;
        const int ntok  = rbase & 8191;
        const int dvl0  = tid >> 4;
        const int t16   = (tid & 15) << 3;
#pragma unroll
        for (int p = 0; p < 8; ++p) {
            const int dvl = (p << 4) + dvl0;
            u16x8 v;
#pragma unroll
            for (int j = 0; j < 8; ++j) v[j] = sm[(t16 + j) * 129 + dvl];
            *(u16x8*)&vto[(size_t)batch * (DIM * SEQ)
                          + (size_t)(cbase + dvl) * SEQ + ntok + t16] = v;
        }
    }
}

// ===========================================================================
// Kernel 2: windowed attention. grid = B*NWIN = 512 blocks, 512 threads.
// ===========================================================================
__global__ __launch_bounds__(512) void k_attn(
    const unsigned short* __restrict__ q,
    const unsigned short* __restrict__ k,
    const unsigned short* __restrict__ vt,
    float* __restrict__ out)
{
    __shared__ __align__(16) unsigned short sm[32768]; // Ks[256][64] swz, later Ps[128][256] swz
    __shared__ float redm[128][4];
    __shared__ float reds[128][4];

    const int bid = blockIdx.x;
    const int b = bid >> 6, w = bid & 63;
    const int tid  = threadIdx.x;
    const int lane = tid & 63, wid = tid >> 6;
    const int l15 = lane & 15, lg = lane >> 4;
    const int wqa = wid >> 2, wka = wid & 3;    // 2x4 wave grid (q, key)
    const int kstart = (w - 1) << 7;            // first key token (may be <0)
    const size_t qrow0 = ((size_t)b << 13) + ((size_t)w << 7);

    f32x4 acc[4][4];
#pragma unroll
    for (int m = 0; m < 4; ++m)
#pragma unroll
        for (int n = 0; n < 4; ++n) acc[m][n] = (f32x4){0.f, 0.f, 0.f, 0.f};

    // ---------------- phase A: S = Q K^T  (128q x 256k, inner 512) ----------
    for (int dstep = 0; dstep < 8; ++dstep) {
        const int dc = dstep << 6;
#pragma unroll
        for (int p = 0; p < 4; ++p) {
            const int r = (p << 6) + (tid >> 3);
            int krow = kstart + r; krow = krow < 0 ? 0 : krow;  // masked anyway
            const int c8 = (tid & 7) << 3;
            u16x8 v = *(const u16x8*)&k[(((size_t)b << 13) + krow) * DIM + dc + c8];
            *(u16x8*)&sm[swz64(r, c8)] = v;
        }
        __syncthreads();
#pragma unroll
        for (int kk = 0; kk < 64; kk += 32) {
            const int cu = kk + (lg << 3);
            bf16x8 af[4], bf[4];
#pragma unroll
            for (int m = 0; m < 4; ++m) {
                const int rq = (wqa << 6) + (m << 4) + l15;
                af[m] = *(const bf16x8*)&q[(qrow0 + rq) * DIM + dc + cu];
            }
#pragma unroll
            for (int n = 0; n < 4; ++n) {
                const int rk = (wka << 6) + (n << 4) + l15;
                bf[n] = *(const bf16x8*)&sm[swz64(rk, cu)];
            }
#pragma unroll
            for (int m = 0; m < 4; ++m)
#pragma unroll
                for (int n = 0; n < 4; ++n)
                    acc[m][n] = __builtin_amdgcn_mfma_f32_16x16x32_bf16(
                        af[m], bf[n], acc[m][n], 0, 0, 0);
        }
        __syncthreads();
    }

    // ---------------- masked block softmax ----------------------------------
    const float scale = 0.04419417382415922f;  // 512^-0.5
    float pm[4][4];
#pragma unroll
    for (int m = 0; m < 4; ++m)
#pragma unroll
        for (int j = 0; j < 4; ++j) {
            const int qr = (wqa << 6) + (m << 4) + (lg << 2) + j;
            float mx = -3.0e38f;
#pragma unroll
            for (int n = 0; n < 4; ++n) {
                const int c = (wka << 6) + (n << 4) + l15;
                const bool keep = (c <= qr + 128) && (w > 0 || c >= 128);
                const float s = keep ? acc[m][n][j] * scale : -INFINITY;
                acc[m][n][j] = s;
                mx = fmaxf(mx, s);
            }
#pragma unroll
            for (int o = 1; o < 16; o <<= 1) mx = fmaxf(mx, __shfl_xor(mx, o));
            pm[m][j] = mx;
        }
    if (l15 == 0) {
#pragma unroll
        for (int m = 0; m < 4; ++m)
#pragma unroll
            for (int j = 0; j < 4; ++j)
                redm[(wqa << 6) + (m << 4) + (lg << 2) + j][wka] = pm[m][j];
    }
    __syncthreads();

    float ls[4][4], gm[4][4];
#pragma unroll
    for (int m = 0; m < 4; ++m)
#pragma unroll
        for (int j = 0; j < 4; ++j) {
            const int qr = (wqa << 6) + (m << 4) + (lg << 2) + j;
            const float g = fmaxf(fmaxf(redm[qr][0], redm[qr][1]),
                                  fmaxf(redm[qr][2], redm[qr][3]));
            gm[m][j] = g;
            float s = 0.f;
#pragma unroll
            for (int n = 0; n < 4; ++n) {
                const float p = __expf(acc[m][n][j] - g);
                acc[m][n][j] = p;
                s += p;
            }
#pragma unroll
            for (int o = 1; o < 16; o <<= 1) s += __shfl_xor(s, o);
            ls[m][j] = s;
        }
    if (l15 == 0) {
#pragma unroll
        for (int m = 0; m < 4; ++m)
#pragma unroll
            for (int j = 0; j < 4; ++j)
                reds[(wqa << 6) + (m << 4) + (lg << 2) + j][wka] = ls[m][j];
    }
    __syncthreads();

    // normalize and store P (bf16) into swizzled LDS [128][256]
#pragma unroll
    for (int m = 0; m < 4; ++m)
#pragma unroll
        for (int j = 0; j < 4; ++j) {
            const int qr = (wqa << 6) + (m << 4) + (lg << 2) + j;
            const float tot = reds[qr][0] + reds[qr][1] + reds[qr][2] + reds[qr][3];
            const float inv = 1.0f / tot;
#pragma unroll
            for (int n = 0; n < 4; ++n) {
                const int c = (wka << 6) + (n << 4) + l15;
                sm[((qr << 8) + c) ^ ((qr & 7) << 3)] = f2b(acc[m][n][j] * inv);
            }
        }
    __syncthreads();

    // ---------------- phase B: O = P V  (128q x 512d, inner 256) ------------
    const int wqb = wid >> 2, wvb = wid & 3;
#pragma unroll
    for (int half = 0; half < 2; ++half) {
        f32x4 oacc[4][4];
#pragma unroll
        for (int m = 0; m < 4; ++m)
#pragma unroll
            for (int n = 0; n < 4; ++n) oacc[m][n] = (f32x4){0.f, 0.f, 0.f, 0.f};
#pragma unroll
        for (int kk = 0; kk < 256; kk += 32) {
            const int klo = kk + (lg << 3);
            bf16x8 af[4], bf[4];
#pragma unroll
            for (int m = 0; m < 4; ++m) {
                const int rq = (wqb << 6) + (m << 4) + l15;
                af[m] = *(const bf16x8*)&sm[((rq << 8) + klo) ^ ((rq & 7) << 3)];
            }
#pragma unroll
            for (int n = 0; n < 4; ++n) {
                const int dv = (half << 8) + (wvb << 6) + (n << 4) + l15;
                int key = kstart + klo; key = key < 0 ? 0 : key;  // P=0 there
                bf[n] = *(const bf16x8*)&vt[(((size_t)b * DIM + dv) << 13) + key];
            }
#pragma unroll
            for (int m = 0; m < 4; ++m)
#pragma unroll
                for (int n = 0; n < 4; ++n)
                    oacc[m][n] = __builtin_amdgcn_mfma_f32_16x16x32_bf16(
                        af[m], bf[n], oacc[m][n], 0, 0, 0);
        }
#pragma unroll
        for (int n = 0; n < 4; ++n) {
            const int dv = (half << 8) + (wvb << 6) + (n << 4) + l15;
#pragma unroll
            for (int m = 0; m < 4; ++m)
#pragma unroll
                for (int j = 0; j < 4; ++j) {
                    const int qr = (wqb << 6) + (m << 4) + (lg << 2) + j;
                    out[(qrow0 + qr) * DIM + dv] = oacc[m][n][j];
                }
        }
    }
}

// ===========================================================================
extern "C" void kernel_launch(void* const* d_in, const int* in_sizes, int n_in,
                              void* d_out, int out_size, void* d_ws, size_t ws_size,
                              hipStream_t stream) {
    (void)in_sizes; (void)n_in; (void)out_size; (void)ws_size;
    const float* x  = (const float*)d_in[0];
    const float* wq = (const float*)d_in[1];
    const float* bq = (const float*)d_in[2];
    const float* wk = (const float*)d_in[3];
    const float* bk = (const float*)d_in[4];
    const float* wv = (const float*)d_in[5];
    const float* bv = (const float*)d_in[6];
    float* out = (float*)d_out;

    unsigned short* qws  = (unsigned short*)d_ws;
    unsigned short* kws  = qws + WSELEM;
    unsigned short* vtws = kws + WSELEM;

    k_qkv<<<6144, 256, 0, stream>>>(x, wq, bq, wk, bk, wv, bv, qws, kws, vtws);
    k_attn<<<512, 512, 0, stream>>>(qws, kws, vtws, out);
}

// Round 2
// 306.634 us; speedup vs baseline: 1.3490x; 1.3490x over previous
//
#include <hip/hip_runtime.h>

// ---------------------------------------------------------------------------
// Local windowed attention, B=8 N=8192 D=512, WS=128, lookback=1.
//   k_cvt : fp32 -> bf16 conversion of x and weights (stored in d_out scratch)
//   k_qkv : m97-structure bf16 MFMA GEMM (global_load_lds w=16, src-swizzled),
//           Q,K row-major bf16; V stored transposed Vt[b][d][n].
//   k_attn: per (b,window): S=QK^T, masked block softmax, O=PV.
// ---------------------------------------------------------------------------

typedef __bf16 bf16x8 __attribute__((ext_vector_type(8)));
typedef float f32x4 __attribute__((ext_vector_type(4)));
typedef unsigned short u16x8 __attribute__((ext_vector_type(8)));

#define BATCH 8
#define SEQ   8192
#define DIM   512
#define NWIN  64
#define TOKS  (BATCH * SEQ)          // 65536
#define WSELEM ((size_t)TOKS * DIM)  // 33554432 elements per Q/K/V buffer

__device__ __forceinline__ unsigned short f2b(float f) {
    union { float f; unsigned int u; } c; c.f = f;
    unsigned int u = c.u;
    return (unsigned short)((u + 0x7FFFu + ((u >> 16) & 1u)) >> 16);
}

// XOR swizzle for [rows][64]-ushort LDS tiles (128B rows): spread 8 rows
// across the 8 16B slots of a 128B line. idx/col in ushort units, col%8==0.
__device__ __forceinline__ int swz64(int row, int col) {
    return (row * 64 + col) ^ ((row & 7) << 3);
}

__device__ __forceinline__ void gload_lds16(const unsigned short* g,
                                            unsigned short* l) {
    __builtin_amdgcn_global_load_lds(
        (const __attribute__((address_space(1))) void*)g,
        (__attribute__((address_space(3))) void*)l, 16, 0, 0);
}

// ===========================================================================
// Kernel 0: fp32 -> bf16 bulk convert (8 f32 / thread / iter, grid-stride)
// ===========================================================================
__global__ __launch_bounds__(256) void k_cvt(const float* __restrict__ s,
                                             unsigned short* __restrict__ d,
                                             int n8) {
    const int stride = gridDim.x * blockDim.x;
    for (int i = blockIdx.x * blockDim.x + threadIdx.x; i < n8; i += stride) {
        const float4 a = ((const float4*)s)[2 * i];
        const float4 b = ((const float4*)s)[2 * i + 1];
        u16x8 v;
        v[0] = f2b(a.x); v[1] = f2b(a.y); v[2] = f2b(a.z); v[3] = f2b(a.w);
        v[4] = f2b(b.x); v[5] = f2b(b.y); v[6] = f2b(b.z); v[7] = f2b(b.w);
        ((u16x8*)d)[i] = v;
    }
}

// ===========================================================================
// Kernel 1: fused QKV projection GEMM (m97 structure).
// grid = 3 * 512 * 4 = 6144, block = 256 (4 waves, 2x2, wave tile 64x64, BK=64)
// A = xb (bf16 row-major), B = wb (bf16 row-major, gemm-major concat).
// Staging: global_load_lds width=16, linear LDS dest + inverse-swizzled
// source so swz64() reads are ~2-way (free) bank aliasing.
// ===========================================================================
__global__ __launch_bounds__(256) void k_qkv(
    const unsigned short* __restrict__ xb, const unsigned short* __restrict__ wb,
    const float* __restrict__ bq, const float* __restrict__ bk,
    const float* __restrict__ bv,
    unsigned short* __restrict__ qo, unsigned short* __restrict__ ko,
    unsigned short* __restrict__ vto)
{
    __shared__ __align__(16) unsigned short sm[16896]; // Xs|Ws; V-epi T[128][129] aliases
    unsigned short* Xs = sm;
    unsigned short* Ws = sm + 8192;

    int bid = (int)blockIdx.x;
    bid = (bid & 7) * 768 + (bid >> 3);   // XCD-contiguous chunks (6144 % 8 == 0)
    const int wsel = bid >> 11;           // 0=Q 1=K 2=V
    const int rem  = bid & 2047;
    const int mt = rem >> 2, nt = rem & 3;
    const int rbase = mt << 7;            // token row base
    const int cbase = nt << 7;            // output feature base

    const unsigned short* __restrict__ xsrc0 = xb + ((size_t)rbase << 9);
    const unsigned short* __restrict__ wsrc0 =
        wb + ((size_t)wsel << 18) + ((size_t)cbase << 9);
    const float* __restrict__ bias = (wsel == 0) ? bq : (wsel == 1) ? bk : bv;

    const int tid  = threadIdx.x;
    const int lane = tid & 63;
    const int wid  = tid >> 6;
    const int wm = wid >> 1, wn = wid & 1;
    const int l15 = lane & 15, lg = lane >> 4;

    f32x4 acc[4][4];
#pragma unroll
    for (int m = 0; m < 4; ++m)
#pragma unroll
        for (int n = 0; n < 4; ++n) acc[m][n] = (f32x4){0.f, 0.f, 0.f, 0.f};

    const int srow = tid >> 3;            // 0..31 (row within 32-row call chunk)
    const int s0   = tid & 7;             // 16B slot within 128B row
    const int ldso = tid << 3;            // ushort offset of this thread's 16B

    for (int ks = 0; ks < 8; ++ks) {
        const int kc = ks << 6;
        // ---- stage A+B tiles: 8x global_load_lds(16B), source-swizzled
#pragma unroll
        for (int i = 0; i < 4; ++i) {
            const int row = (i << 5) + srow;
            const int gs  = (s0 ^ (row & 7)) << 3;
            gload_lds16(xsrc0 + ((size_t)row << 9) + kc + gs, Xs + (i << 11) + ldso);
            gload_lds16(wsrc0 + ((size_t)row << 9) + kc + gs, Ws + (i << 11) + ldso);
        }
        __syncthreads();   // vmcnt(0) drain + barrier (m97 structure)
        // ---- 32 MFMA on the 64-wide K chunk
#pragma unroll
        for (int kk = 0; kk < 64; kk += 32) {
            const int cu = kk + (lg << 3);
            bf16x8 af[4], bfr[4];
#pragma unroll
            for (int m = 0; m < 4; ++m)
                af[m] = *(const bf16x8*)&Xs[swz64((wm << 6) + (m << 4) + l15, cu)];
#pragma unroll
            for (int n = 0; n < 4; ++n)
                bfr[n] = *(const bf16x8*)&Ws[swz64((wn << 6) + (n << 4) + l15, cu)];
#pragma unroll
            for (int m = 0; m < 4; ++m)
#pragma unroll
                for (int n = 0; n < 4; ++n)
                    acc[m][n] = __builtin_amdgcn_mfma_f32_16x16x32_bf16(
                        af[m], bfr[n], acc[m][n], 0, 0, 0);
        }
        __syncthreads();
    }

    if (wsel < 2) {
        // ---- Q/K epilogue: row-major bf16 store
        unsigned short* __restrict__ out = wsel ? ko : qo;
#pragma unroll
        for (int n = 0; n < 4; ++n) {
            const int col = cbase + (wn << 6) + (n << 4) + l15;
            const float bv_ = bias[col];
#pragma unroll
            for (int m = 0; m < 4; ++m)
#pragma unroll
                for (int j = 0; j < 4; ++j) {
                    const int row = rbase + (wm << 6) + (m << 4) + (lg << 2) + j;
                    out[(size_t)row * DIM + col] = f2b(acc[m][n][j] + bv_);
                }
        }
    } else {
        // ---- V epilogue: transpose via LDS T[128][129], store Vt[b][d][n]
#pragma unroll
        for (int n = 0; n < 4; ++n) {
            const int dv = (wn << 6) + (n << 4) + l15;
            const float bv_ = bias[cbase + dv];
#pragma unroll
            for (int m = 0; m < 4; ++m)
#pragma unroll
                for (int j = 0; j < 4; ++j) {
                    const int tok = (wm << 6) + (m << 4) + (lg << 2) + j;
                    sm[tok * 129 + dv] = f2b(acc[m][n][j] + bv_);
                }
        }
        __syncthreads();
        const int batch = rbase >> 13;
        const int ntok  = rbase & 8191;
        const int dvl0  = tid >> 4;
        const int t16   = (tid & 15) << 3;
#pragma unroll
        for (int p = 0; p < 8; ++p) {
            const int dvl = (p << 4) + dvl0;
            u16x8 v;
#pragma unroll
            for (int j = 0; j < 8; ++j) v[j] = sm[(t16 + j) * 129 + dvl];
            *(u16x8*)&vto[(size_t)batch * (DIM * SEQ)
                          + (size_t)(cbase + dvl) * SEQ + ntok + t16] = v;
        }
    }
}

// ===========================================================================
// Kernel 2: windowed attention. grid = B*NWIN = 512 blocks, 512 threads.
// ===========================================================================
__global__ __launch_bounds__(512) void k_attn(
    const unsigned short* __restrict__ q,
    const unsigned short* __restrict__ k,
    const unsigned short* __restrict__ vt,
    float* __restrict__ out)
{
    __shared__ __align__(16) unsigned short sm[32768]; // Ks[256][64] swz, later Ps[128][256] swz
    __shared__ float redm[128][4];
    __shared__ float reds[128][4];

    const int bid = blockIdx.x;
    const int b = bid >> 6, w = bid & 63;
    const int tid  = threadIdx.x;
    const int lane = tid & 63, wid = tid >> 6;
    const int l15 = lane & 15, lg = lane >> 4;
    const int wqa = wid >> 2, wka = wid & 3;    // 2x4 wave grid (q, key)
    const int kstart = (w - 1) << 7;            // first key token (may be <0)
    const size_t qrow0 = ((size_t)b << 13) + ((size_t)w << 7);

    f32x4 acc[4][4];
#pragma unroll
    for (int m = 0; m < 4; ++m)
#pragma unroll
        for (int n = 0; n < 4; ++n) acc[m][n] = (f32x4){0.f, 0.f, 0.f, 0.f};

    // ---------------- phase A: S = Q K^T  (128q x 256k, inner 512) ----------
    for (int dstep = 0; dstep < 8; ++dstep) {
        const int dc = dstep << 6;
#pragma unroll
        for (int p = 0; p < 4; ++p) {
            const int r = (p << 6) + (tid >> 3);
            int krow = kstart + r; krow = krow < 0 ? 0 : krow;  // masked anyway
            const int c8 = (tid & 7) << 3;
            u16x8 v = *(const u16x8*)&k[(((size_t)b << 13) + krow) * DIM + dc + c8];
            *(u16x8*)&sm[swz64(r, c8)] = v;
        }
        __syncthreads();
#pragma unroll
        for (int kk = 0; kk < 64; kk += 32) {
            const int cu = kk + (lg << 3);
            bf16x8 af[4], bf[4];
#pragma unroll
            for (int m = 0; m < 4; ++m) {
                const int rq = (wqa << 6) + (m << 4) + l15;
                af[m] = *(const bf16x8*)&q[(qrow0 + rq) * DIM + dc + cu];
            }
#pragma unroll
            for (int n = 0; n < 4; ++n) {
                const int rk = (wka << 6) + (n << 4) + l15;
                bf[n] = *(const bf16x8*)&sm[swz64(rk, cu)];
            }
#pragma unroll
            for (int m = 0; m < 4; ++m)
#pragma unroll
                for (int n = 0; n < 4; ++n)
                    acc[m][n] = __builtin_amdgcn_mfma_f32_16x16x32_bf16(
                        af[m], bf[n], acc[m][n], 0, 0, 0);
        }
        __syncthreads();
    }

    // ---------------- masked block softmax ----------------------------------
    const float scale = 0.04419417382415922f;  // 512^-0.5
    float pm[4][4];
#pragma unroll
    for (int m = 0; m < 4; ++m)
#pragma unroll
        for (int j = 0; j < 4; ++j) {
            const int qr = (wqa << 6) + (m << 4) + (lg << 2) + j;
            float mx = -3.0e38f;
#pragma unroll
            for (int n = 0; n < 4; ++n) {
                const int c = (wka << 6) + (n << 4) + l15;
                const bool keep = (c <= qr + 128) && (w > 0 || c >= 128);
                const float s = keep ? acc[m][n][j] * scale : -INFINITY;
                acc[m][n][j] = s;
                mx = fmaxf(mx, s);
            }
#pragma unroll
            for (int o = 1; o < 16; o <<= 1) mx = fmaxf(mx, __shfl_xor(mx, o));
            pm[m][j] = mx;
        }
    if (l15 == 0) {
#pragma unroll
        for (int m = 0; m < 4; ++m)
#pragma unroll
            for (int j = 0; j < 4; ++j)
                redm[(wqa << 6) + (m << 4) + (lg << 2) + j][wka] = pm[m][j];
    }
    __syncthreads();

    float ls[4][4];
#pragma unroll
    for (int m = 0; m < 4; ++m)
#pragma unroll
        for (int j = 0; j < 4; ++j) {
            const int qr = (wqa << 6) + (m << 4) + (lg << 2) + j;
            const float g = fmaxf(fmaxf(redm[qr][0], redm[qr][1]),
                                  fmaxf(redm[qr][2], redm[qr][3]));
            float s = 0.f;
#pragma unroll
            for (int n = 0; n < 4; ++n) {
                const float p = __expf(acc[m][n][j] - g);
                acc[m][n][j] = p;
                s += p;
            }
#pragma unroll
            for (int o = 1; o < 16; o <<= 1) s += __shfl_xor(s, o);
            ls[m][j] = s;
        }
    if (l15 == 0) {
#pragma unroll
        for (int m = 0; m < 4; ++m)
#pragma unroll
            for (int j = 0; j < 4; ++j)
                reds[(wqa << 6) + (m << 4) + (lg << 2) + j][wka] = ls[m][j];
    }
    __syncthreads();

    // normalize and store P (bf16) into swizzled LDS [128][256]
#pragma unroll
    for (int m = 0; m < 4; ++m)
#pragma unroll
        for (int j = 0; j < 4; ++j) {
            const int qr = (wqa << 6) + (m << 4) + (lg << 2) + j;
            const float tot = reds[qr][0] + reds[qr][1] + reds[qr][2] + reds[qr][3];
            const float inv = 1.0f / tot;
#pragma unroll
            for (int n = 0; n < 4; ++n) {
                const int c = (wka << 6) + (n << 4) + l15;
                sm[((qr << 8) + c) ^ ((qr & 7) << 3)] = f2b(acc[m][n][j] * inv);
            }
        }
    __syncthreads();

    // ---------------- phase B: O = P V  (128q x 512d, inner 256) ------------
    const int wqb = wid >> 2, wvb = wid & 3;
#pragma unroll
    for (int half = 0; half < 2; ++half) {
        f32x4 oacc[4][4];
#pragma unroll
        for (int m = 0; m < 4; ++m)
#pragma unroll
            for (int n = 0; n < 4; ++n) oacc[m][n] = (f32x4){0.f, 0.f, 0.f, 0.f};
#pragma unroll
        for (int kk = 0; kk < 256; kk += 32) {
            const int klo = kk + (lg << 3);
            bf16x8 af[4], bf[4];
#pragma unroll
            for (int m = 0; m < 4; ++m) {
                const int rq = (wqb << 6) + (m << 4) + l15;
                af[m] = *(const bf16x8*)&sm[((rq << 8) + klo) ^ ((rq & 7) << 3)];
            }
#pragma unroll
            for (int n = 0; n < 4; ++n) {
                const int dv = (half << 8) + (wvb << 6) + (n << 4) + l15;
                int key = kstart + klo; key = key < 0 ? 0 : key;  // P=0 there
                bf[n] = *(const bf16x8*)&vt[(((size_t)b * DIM + dv) << 13) + key];
            }
#pragma unroll
            for (int m = 0; m < 4; ++m)
#pragma unroll
                for (int n = 0; n < 4; ++n)
                    oacc[m][n] = __builtin_amdgcn_mfma_f32_16x16x32_bf16(
                        af[m], bf[n], oacc[m][n], 0, 0, 0);
        }
#pragma unroll
        for (int n = 0; n < 4; ++n) {
            const int dv = (half << 8) + (wvb << 6) + (n << 4) + l15;
#pragma unroll
            for (int m = 0; m < 4; ++m)
#pragma unroll
                for (int j = 0; j < 4; ++j) {
                    const int qr = (wqb << 6) + (m << 4) + (lg << 2) + j;
                    out[(qrow0 + qr) * DIM + dv] = oacc[m][n][j];
                }
        }
    }
}

// ===========================================================================
extern "C" void kernel_launch(void* const* d_in, const int* in_sizes, int n_in,
                              void* d_out, int out_size, void* d_ws, size_t ws_size,
                              hipStream_t stream) {
    (void)in_sizes; (void)n_in; (void)out_size; (void)ws_size;
    const float* x  = (const float*)d_in[0];
    const float* wq = (const float*)d_in[1];
    const float* bq = (const float*)d_in[2];
    const float* wk = (const float*)d_in[3];
    const float* bk = (const float*)d_in[4];
    const float* wv = (const float*)d_in[5];
    const float* bv = (const float*)d_in[6];
    float* out = (float*)d_out;

    // bf16 scratch for Q/K/Vt lives in d_ws (192 MiB, proven available).
    unsigned short* qws  = (unsigned short*)d_ws;
    unsigned short* kws  = qws + WSELEM;
    unsigned short* vtws = kws + WSELEM;

    // xb (64 MiB) + wb (1.5 MiB) live in d_out (128 MiB) — consumed by k_qkv
    // before k_attn overwrites d_out with the final output (stream-ordered).
    unsigned short* xbuf = (unsigned short*)d_out;
    unsigned short* wbuf = xbuf + WSELEM;

    k_cvt<<<2048, 256, 0, stream>>>(x, xbuf, (int)(WSELEM / 8));
    k_cvt<<<128, 256, 0, stream>>>(wq, wbuf, DIM * DIM / 8);
    k_cvt<<<128, 256, 0, stream>>>(wk, wbuf + DIM * DIM, DIM * DIM / 8);
    k_cvt<<<128, 256, 0, stream>>>(wv, wbuf + 2 * DIM * DIM, DIM * DIM / 8);
    k_qkv<<<6144, 256, 0, stream>>>(xbuf, wbuf, bq, bk, bv, qws, kws, vtws);
    k_attn<<<512, 512, 0, stream>>>(qws, kws, vtws, out);
}

// Round 3
// 283.338 us; speedup vs baseline: 1.4600x; 1.0822x over previous
//
#include <hip/hip_runtime.h>

// ---------------------------------------------------------------------------
// Local windowed attention, B=8 N=8192 D=512, WS=128, lookback=1.
//   k_cvt : fp32 -> bf16 convert of x and weights (scratch in d_out)
//   k_qkv : merged Q/K/V projection GEMM — one block does all 3 ops for a
//           128x128 tile, X staged once per K-step (global_load_lds w=16,
//           src-swizzled). Q,K row-major bf16; V transposed Vt[b][d][n].
//   k_attn: per (b,window): S=QK^T (K via global_load_lds, 128-wide chunks),
//           masked block softmax, O=PV (P in LDS, V direct from Vt).
// ---------------------------------------------------------------------------

typedef __bf16 bf16x8 __attribute__((ext_vector_type(8)));
typedef float f32x4 __attribute__((ext_vector_type(4)));
typedef unsigned short u16x8 __attribute__((ext_vector_type(8)));

#define BATCH 8
#define SEQ   8192
#define DIM   512
#define NWIN  64
#define TOKS  (BATCH * SEQ)          // 65536
#define WSELEM ((size_t)TOKS * DIM)  // 33554432 elements per Q/K/V buffer

__device__ __forceinline__ unsigned short f2b(float f) {
    union { float f; unsigned int u; } c; c.f = f;
    unsigned int u = c.u;
    return (unsigned short)((u + 0x7FFFu + ((u >> 16) & 1u)) >> 16);
}

// XOR swizzles (ushort units). Rows of 64/128 ushorts = 128/256 B.
__device__ __forceinline__ int swz64(int row, int col) {   // 8 16B slots
    return (row * 64 + col) ^ ((row & 7) << 3);
}
__device__ __forceinline__ int swz128(int row, int col) {  // 16 16B slots
    return (row * 128 + col) ^ ((row & 15) << 3);
}

__device__ __forceinline__ void gload_lds16(const unsigned short* g,
                                            unsigned short* l) {
    __builtin_amdgcn_global_load_lds(
        (const __attribute__((address_space(1))) void*)g,
        (__attribute__((address_space(3))) void*)l, 16, 0, 0);
}

// ===========================================================================
// Kernel 0: fp32 -> bf16 bulk convert (8 f32 / thread / iter, grid-stride)
// ===========================================================================
__global__ __launch_bounds__(256) void k_cvt(const float* __restrict__ s,
                                             unsigned short* __restrict__ d,
                                             int n8) {
    const int stride = gridDim.x * blockDim.x;
    for (int i = blockIdx.x * blockDim.x + threadIdx.x; i < n8; i += stride) {
        const float4 a = ((const float4*)s)[2 * i];
        const float4 b = ((const float4*)s)[2 * i + 1];
        u16x8 v;
        v[0] = f2b(a.x); v[1] = f2b(a.y); v[2] = f2b(a.z); v[3] = f2b(a.w);
        v[4] = f2b(b.x); v[5] = f2b(b.y); v[6] = f2b(b.z); v[7] = f2b(b.w);
        ((u16x8*)d)[i] = v;
    }
}

// ===========================================================================
// Kernel 1: merged QKV projection GEMM. grid = 512*4 = 2048, block = 256
// (4 waves, 2x2, wave tile 64x64). One block -> Q,K,V 128x128 tiles: X is
// staged once per K-step and reused by 96 MFMA (3 ops x 32).
// ===========================================================================
__global__ __launch_bounds__(256, 2) void k_qkv(
    const unsigned short* __restrict__ xb, const unsigned short* __restrict__ wb,
    const float* __restrict__ bq, const float* __restrict__ bk,
    const float* __restrict__ bv,
    unsigned short* __restrict__ qo, unsigned short* __restrict__ ko,
    unsigned short* __restrict__ vto)
{
    __shared__ __align__(16) unsigned short sm[32768]; // Xs|Wq|Wk|Wv (4x16KB); V-epi T[128][129] aliases
    unsigned short* Xs = sm;

    int bid = (int)blockIdx.x;
    bid = (bid & 7) * 256 + (bid >> 3);   // XCD-contiguous chunks (2048 % 8 == 0)
    const int mt = bid >> 2, nt = bid & 3;
    const int rbase = mt << 7;            // token row base
    const int cbase = nt << 7;            // output feature base

    const unsigned short* __restrict__ xsrc0 = xb + ((size_t)rbase << 9);
    const unsigned short* __restrict__ wsrc0 = wb + ((size_t)cbase << 9);

    const int tid  = threadIdx.x;
    const int lane = tid & 63;
    const int wid  = tid >> 6;
    const int wm = wid >> 1, wn = wid & 1;
    const int l15 = lane & 15, lg = lane >> 4;

    f32x4 acc[3][4][4];
#pragma unroll
    for (int s = 0; s < 3; ++s)
#pragma unroll
        for (int m = 0; m < 4; ++m)
#pragma unroll
            for (int n = 0; n < 4; ++n) acc[s][m][n] = (f32x4){0.f, 0.f, 0.f, 0.f};

    const int srow = tid >> 3;            // 0..31
    const int gs   = ((tid & 7) ^ (srow & 7)) << 3;  // src 16B slot (swizzled)
    const int ldso = tid << 3;            // ushort offset of this thread's 16B

    for (int ks = 0; ks < 8; ++ks) {
        const int kc = ks << 6;
        // ---- stage X once + 3 W tiles: 16x global_load_lds(16B)/thread
#pragma unroll
        for (int i = 0; i < 4; ++i) {
            const int row = (i << 5) + srow;
            gload_lds16(xsrc0 + ((size_t)row << 9) + kc + gs, Xs + (i << 11) + ldso);
        }
#pragma unroll
        for (int ws = 0; ws < 3; ++ws) {
#pragma unroll
            for (int i = 0; i < 4; ++i) {
                const int row = (i << 5) + srow;
                gload_lds16(wsrc0 + ((size_t)ws << 18) + ((size_t)row << 9) + kc + gs,
                            sm + 8192 + (ws << 13) + (i << 11) + ldso);
            }
        }
        __syncthreads();   // vmcnt(0) drain + barrier
        // ---- 96 MFMA on the 64-wide K chunk (af reused across 3 ops)
#pragma unroll
        for (int kk = 0; kk < 64; kk += 32) {
            const int cu = kk + (lg << 3);
            bf16x8 af[4];
#pragma unroll
            for (int m = 0; m < 4; ++m)
                af[m] = *(const bf16x8*)&Xs[swz64((wm << 6) + (m << 4) + l15, cu)];
#pragma unroll
            for (int ws = 0; ws < 3; ++ws) {
                const unsigned short* Wsb = sm + 8192 + (ws << 13);
                bf16x8 bfr[4];
#pragma unroll
                for (int n = 0; n < 4; ++n)
                    bfr[n] = *(const bf16x8*)&Wsb[swz64((wn << 6) + (n << 4) + l15, cu)];
#pragma unroll
                for (int m = 0; m < 4; ++m)
#pragma unroll
                    for (int n = 0; n < 4; ++n)
                        acc[ws][m][n] = __builtin_amdgcn_mfma_f32_16x16x32_bf16(
                            af[m], bfr[n], acc[ws][m][n], 0, 0, 0);
            }
        }
        __syncthreads();
    }

    // ---- Q/K epilogues: row-major bf16 stores
#pragma unroll
    for (int ws = 0; ws < 2; ++ws) {
        unsigned short* __restrict__ out = ws ? ko : qo;
        const float* __restrict__ bias = ws ? bk : bq;
#pragma unroll
        for (int n = 0; n < 4; ++n) {
            const int col = cbase + (wn << 6) + (n << 4) + l15;
            const float bv_ = bias[col];
#pragma unroll
            for (int m = 0; m < 4; ++m)
#pragma unroll
                for (int j = 0; j < 4; ++j) {
                    const int row = rbase + (wm << 6) + (m << 4) + (lg << 2) + j;
                    out[(size_t)row * DIM + col] = f2b(acc[ws][m][n][j] + bv_);
                }
        }
    }
    // ---- V epilogue: transpose via LDS T[128][129], store Vt[b][d][n]
    // (all LDS MFMA reads completed at the K-loop's final barrier)
#pragma unroll
    for (int n = 0; n < 4; ++n) {
        const int dv = (wn << 6) + (n << 4) + l15;
        const float bv_ = bv[cbase + dv];
#pragma unroll
        for (int m = 0; m < 4; ++m)
#pragma unroll
            for (int j = 0; j < 4; ++j) {
                const int tok = (wm << 6) + (m << 4) + (lg << 2) + j;
                sm[tok * 129 + dv] = f2b(acc[2][m][n][j] + bv_);
            }
    }
    __syncthreads();
    {
        const int batch = rbase >> 13;
        const int ntok  = rbase & 8191;
        const int dvl0  = tid >> 4;
        const int t16   = (tid & 15) << 3;
#pragma unroll
        for (int p = 0; p < 8; ++p) {
            const int dvl = (p << 4) + dvl0;
            u16x8 v;
#pragma unroll
            for (int j = 0; j < 8; ++j) v[j] = sm[(t16 + j) * 129 + dvl];
            *(u16x8*)&vto[(size_t)batch * (DIM * SEQ)
                          + (size_t)(cbase + dvl) * SEQ + ntok + t16] = v;
        }
    }
}

// ===========================================================================
// Kernel 2: windowed attention. grid = B*NWIN = 512 blocks, 512 threads.
// ===========================================================================
__global__ __launch_bounds__(512) void k_attn(
    const unsigned short* __restrict__ q,
    const unsigned short* __restrict__ k,
    const unsigned short* __restrict__ vt,
    float* __restrict__ out)
{
    __shared__ __align__(16) unsigned short sm[32768]; // Ks[256][128] swz16 / later Ps[128][256] swz8
    __shared__ float redm[128][4];
    __shared__ float reds[128][4];

    int bid = (int)blockIdx.x;
    bid = (bid & 7) * 64 + (bid >> 3);    // XCD-chunked: one batch per chunk
    const int b = bid >> 6, w = bid & 63;
    const int tid  = threadIdx.x;
    const int lane = tid & 63, wid = tid >> 6;
    const int l15 = lane & 15, lg = lane >> 4;
    const int wqa = wid >> 2, wka = wid & 3;    // 2x4 wave grid (q, key)
    const int kstart = (w - 1) << 7;            // first key token (may be <0)
    const size_t qrow0 = ((size_t)b << 13) + ((size_t)w << 7);

    f32x4 acc[4][4];
#pragma unroll
    for (int m = 0; m < 4; ++m)
#pragma unroll
        for (int n = 0; n < 4; ++n) acc[m][n] = (f32x4){0.f, 0.f, 0.f, 0.f};

    const int srA = tid >> 4;                   // 0..31
    const int gsA = (((tid & 15) ^ (srA & 15)) << 3); // src slot (swizzled)

    // ---------------- phase A: S = Q K^T  (128q x 256k, inner 512) ----------
    for (int dstep = 0; dstep < 4; ++dstep) {
        const int dc = dstep << 7;
        // stage K[256][dc..dc+128) via global_load_lds, src-swizzled
#pragma unroll
        for (int i = 0; i < 8; ++i) {
            const int r = (i << 5) + srA;
            int krow = kstart + r; krow = krow < 0 ? 0 : krow;  // masked anyway
            gload_lds16(k + (((size_t)b << 13) + krow) * DIM + dc + gsA,
                        sm + (i << 12) + (tid << 3));
        }
        __syncthreads();
#pragma unroll
        for (int kk = 0; kk < 128; kk += 32) {
            const int cu = kk + (lg << 3);
            bf16x8 af[4], bf[4];
#pragma unroll
            for (int m = 0; m < 4; ++m) {
                const int rq = (wqa << 6) + (m << 4) + l15;
                af[m] = *(const bf16x8*)&q[(qrow0 + rq) * DIM + dc + cu];
            }
#pragma unroll
            for (int n = 0; n < 4; ++n) {
                const int rk = (wka << 6) + (n << 4) + l15;
                bf[n] = *(const bf16x8*)&sm[swz128(rk, cu)];
            }
#pragma unroll
            for (int m = 0; m < 4; ++m)
#pragma unroll
                for (int n = 0; n < 4; ++n)
                    acc[m][n] = __builtin_amdgcn_mfma_f32_16x16x32_bf16(
                        af[m], bf[n], acc[m][n], 0, 0, 0);
        }
        __syncthreads();
    }

    // ---------------- masked block softmax ----------------------------------
    const float scale = 0.04419417382415922f;  // 512^-0.5
    float pm[4][4];
#pragma unroll
    for (int m = 0; m < 4; ++m)
#pragma unroll
        for (int j = 0; j < 4; ++j) {
            const int qr = (wqa << 6) + (m << 4) + (lg << 2) + j;
            float mx = -3.0e38f;
#pragma unroll
            for (int n = 0; n < 4; ++n) {
                const int c = (wka << 6) + (n << 4) + l15;
                const bool keep = (c <= qr + 128) && (w > 0 || c >= 128);
                const float s = keep ? acc[m][n][j] * scale : -INFINITY;
                acc[m][n][j] = s;
                mx = fmaxf(mx, s);
            }
#pragma unroll
            for (int o = 1; o < 16; o <<= 1) mx = fmaxf(mx, __shfl_xor(mx, o));
            pm[m][j] = mx;
        }
    if (l15 == 0) {
#pragma unroll
        for (int m = 0; m < 4; ++m)
#pragma unroll
            for (int j = 0; j < 4; ++j)
                redm[(wqa << 6) + (m << 4) + (lg << 2) + j][wka] = pm[m][j];
    }
    __syncthreads();

    float ls[4][4];
#pragma unroll
    for (int m = 0; m < 4; ++m)
#pragma unroll
        for (int j = 0; j < 4; ++j) {
            const int qr = (wqa << 6) + (m << 4) + (lg << 2) + j;
            const float g = fmaxf(fmaxf(redm[qr][0], redm[qr][1]),
                                  fmaxf(redm[qr][2], redm[qr][3]));
            float s = 0.f;
#pragma unroll
            for (int n = 0; n < 4; ++n) {
                const float p = __expf(acc[m][n][j] - g);
                acc[m][n][j] = p;
                s += p;
            }
#pragma unroll
            for (int o = 1; o < 16; o <<= 1) s += __shfl_xor(s, o);
            ls[m][j] = s;
        }
    if (l15 == 0) {
#pragma unroll
        for (int m = 0; m < 4; ++m)
#pragma unroll
            for (int j = 0; j < 4; ++j)
                reds[(wqa << 6) + (m << 4) + (lg << 2) + j][wka] = ls[m][j];
    }
    __syncthreads();

    // normalize and store P (bf16) into swizzled LDS [128][256]
#pragma unroll
    for (int m = 0; m < 4; ++m)
#pragma unroll
        for (int j = 0; j < 4; ++j) {
            const int qr = (wqa << 6) + (m << 4) + (lg << 2) + j;
            const float tot = reds[qr][0] + reds[qr][1] + reds[qr][2] + reds[qr][3];
            const float inv = 1.0f / tot;
#pragma unroll
            for (int n = 0; n < 4; ++n) {
                const int c = (wka << 6) + (n << 4) + l15;
                sm[((qr << 8) + c) ^ ((qr & 7) << 3)] = f2b(acc[m][n][j] * inv);
            }
        }
    __syncthreads();

    // ---------------- phase B: O = P V  (128q x 512d, inner 256) ------------
    const int wqb = wid >> 2, wvb = wid & 3;
#pragma unroll
    for (int half = 0; half < 2; ++half) {
        f32x4 oacc[4][4];
#pragma unroll
        for (int m = 0; m < 4; ++m)
#pragma unroll
            for (int n = 0; n < 4; ++n) oacc[m][n] = (f32x4){0.f, 0.f, 0.f, 0.f};
#pragma unroll
        for (int kk = 0; kk < 256; kk += 32) {
            const int klo = kk + (lg << 3);
            bf16x8 af[4], bf[4];
#pragma unroll
            for (int m = 0; m < 4; ++m) {
                const int rq = (wqb << 6) + (m << 4) + l15;
                af[m] = *(const bf16x8*)&sm[((rq << 8) + klo) ^ ((rq & 7) << 3)];
            }
            int key = kstart + klo; key = key < 0 ? 0 : key;  // P=0 there
#pragma unroll
            for (int n = 0; n < 4; ++n) {
                const int dv = (half << 8) + (wvb << 6) + (n << 4) + l15;
                bf[n] = *(const bf16x8*)&vt[(((size_t)b * DIM + dv) << 13) + key];
            }
#pragma unroll
            for (int m = 0; m < 4; ++m)
#pragma unroll
                for (int n = 0; n < 4; ++n)
                    oacc[m][n] = __builtin_amdgcn_mfma_f32_16x16x32_bf16(
                        af[m], bf[n], oacc[m][n], 0, 0, 0);
        }
#pragma unroll
        for (int n = 0; n < 4; ++n) {
            const int dv = (half << 8) + (wvb << 6) + (n << 4) + l15;
#pragma unroll
            for (int m = 0; m < 4; ++m)
#pragma unroll
                for (int j = 0; j < 4; ++j) {
                    const int qr = (wqb << 6) + (m << 4) + (lg << 2) + j;
                    out[(qrow0 + qr) * DIM + dv] = oacc[m][n][j];
                }
        }
    }
}

// ===========================================================================
extern "C" void kernel_launch(void* const* d_in, const int* in_sizes, int n_in,
                              void* d_out, int out_size, void* d_ws, size_t ws_size,
                              hipStream_t stream) {
    (void)in_sizes; (void)n_in; (void)out_size; (void)ws_size;
    const float* x  = (const float*)d_in[0];
    const float* wq = (const float*)d_in[1];
    const float* bq = (const float*)d_in[2];
    const float* wk = (const float*)d_in[3];
    const float* bk = (const float*)d_in[4];
    const float* wv = (const float*)d_in[5];
    const float* bv = (const float*)d_in[6];
    float* out = (float*)d_out;

    // bf16 scratch for Q/K/Vt lives in d_ws (192 MiB, proven available).
    unsigned short* qws  = (unsigned short*)d_ws;
    unsigned short* kws  = qws + WSELEM;
    unsigned short* vtws = kws + WSELEM;

    // xb (64 MiB) + wb (1.5 MiB) live in d_out (128 MiB) — consumed by k_qkv
    // before k_attn overwrites d_out with the final output (stream-ordered).
    unsigned short* xbuf = (unsigned short*)d_out;
    unsigned short* wbuf = xbuf + WSELEM;

    k_cvt<<<2048, 256, 0, stream>>>(x, xbuf, (int)(WSELEM / 8));
    k_cvt<<<128, 256, 0, stream>>>(wq, wbuf, DIM * DIM / 8);
    k_cvt<<<128, 256, 0, stream>>>(wk, wbuf + DIM * DIM, DIM * DIM / 8);
    k_cvt<<<128, 256, 0, stream>>>(wv, wbuf + 2 * DIM * DIM, DIM * DIM / 8);
    k_qkv<<<2048, 256, 0, stream>>>(xbuf, wbuf, bq, bk, bv, qws, kws, vtws);
    k_attn<<<512, 512, 0, stream>>>(qws, kws, vtws, out);
}

// Round 4
// 238.510 us; speedup vs baseline: 1.7344x; 1.1879x over previous
//
#include <hip/hip_runtime.h>

// ---------------------------------------------------------------------------
// Local windowed attention, B=8 N=8192 D=512, WS=128, lookback=1.
//   k_cvt : fp32 -> bf16 convert of x and weights (scratch in d_out)
//   k_qkv : merged Q/K/V projection GEMM (X staged once per K-step).
//           Q,K row-major bf16; V in tiled-transpose Vt3[b][key/32][dv][key%32].
//   k_attn: per (b,window), 8 waves x 16 q-rows. Per-wave softmax (no cross-
//           wave barriers), K pipelined in LDS, V staged via Vt3 (coalesced),
//           P in wave-private LDS, normalization deferred to epilogue.
// ---------------------------------------------------------------------------

typedef __bf16 bf16x8 __attribute__((ext_vector_type(8)));
typedef float f32x4 __attribute__((ext_vector_type(4)));
typedef unsigned short u16x8 __attribute__((ext_vector_type(8)));

#define BATCH 8
#define SEQ   8192
#define DIM   512
#define NWIN  64
#define TOKS  (BATCH * SEQ)          // 65536
#define WSELEM ((size_t)TOKS * DIM)  // 33554432 elements per Q/K/V buffer

__device__ __forceinline__ unsigned short f2b(float f) {
    union { float f; unsigned int u; } c; c.f = f;
    unsigned int u = c.u;
    return (unsigned short)((u + 0x7FFFu + ((u >> 16) & 1u)) >> 16);
}

// XOR swizzle for [rows][64]-ushort LDS tiles (128B rows).
__device__ __forceinline__ int swz64(int row, int col) {
    return (row * 64 + col) ^ ((row & 7) << 3);
}

__device__ __forceinline__ void gload_lds16(const unsigned short* g,
                                            unsigned short* l) {
    __builtin_amdgcn_global_load_lds(
        (const __attribute__((address_space(1))) void*)g,
        (__attribute__((address_space(3))) void*)l, 16, 0, 0);
}

// ===========================================================================
// Kernel 0: fp32 -> bf16 bulk convert
// ===========================================================================
__global__ __launch_bounds__(256) void k_cvt(const float* __restrict__ s,
                                             unsigned short* __restrict__ d,
                                             int n8) {
    const int stride = gridDim.x * blockDim.x;
    for (int i = blockIdx.x * blockDim.x + threadIdx.x; i < n8; i += stride) {
        const float4 a = ((const float4*)s)[2 * i];
        const float4 b = ((const float4*)s)[2 * i + 1];
        u16x8 v;
        v[0] = f2b(a.x); v[1] = f2b(a.y); v[2] = f2b(a.z); v[3] = f2b(a.w);
        v[4] = f2b(b.x); v[5] = f2b(b.y); v[6] = f2b(b.z); v[7] = f2b(b.w);
        ((u16x8*)d)[i] = v;
    }
}

// ===========================================================================
// Kernel 1: merged QKV projection GEMM. grid = 2048, block = 256.
// ===========================================================================
__global__ __launch_bounds__(256, 2) void k_qkv(
    const unsigned short* __restrict__ xb, const unsigned short* __restrict__ wb,
    const float* __restrict__ bq, const float* __restrict__ bk,
    const float* __restrict__ bv,
    unsigned short* __restrict__ qo, unsigned short* __restrict__ ko,
    unsigned short* __restrict__ vto)
{
    __shared__ __align__(16) unsigned short sm[32768]; // Xs|Wq|Wk|Wv; V-epi T[128][129] aliases
    unsigned short* Xs = sm;

    int bid = (int)blockIdx.x;
    bid = (bid & 7) * 256 + (bid >> 3);   // XCD-contiguous chunks
    const int mt = bid >> 2, nt = bid & 3;
    const int rbase = mt << 7;            // token row base
    const int cbase = nt << 7;            // output feature base

    const unsigned short* __restrict__ xsrc0 = xb + ((size_t)rbase << 9);
    const unsigned short* __restrict__ wsrc0 = wb + ((size_t)cbase << 9);

    const int tid  = threadIdx.x;
    const int lane = tid & 63;
    const int wid  = tid >> 6;
    const int wm = wid >> 1, wn = wid & 1;
    const int l15 = lane & 15, lg = lane >> 4;

    f32x4 acc[3][4][4];
#pragma unroll
    for (int s = 0; s < 3; ++s)
#pragma unroll
        for (int m = 0; m < 4; ++m)
#pragma unroll
            for (int n = 0; n < 4; ++n) acc[s][m][n] = (f32x4){0.f, 0.f, 0.f, 0.f};

    const int srow = tid >> 3;            // 0..31
    const int gs   = ((tid & 7) ^ (srow & 7)) << 3;  // src 16B slot (swizzled)
    const int ldso = tid << 3;

    for (int ks = 0; ks < 8; ++ks) {
        const int kc = ks << 6;
#pragma unroll
        for (int i = 0; i < 4; ++i) {
            const int row = (i << 5) + srow;
            gload_lds16(xsrc0 + ((size_t)row << 9) + kc + gs, Xs + (i << 11) + ldso);
        }
#pragma unroll
        for (int ws = 0; ws < 3; ++ws) {
#pragma unroll
            for (int i = 0; i < 4; ++i) {
                const int row = (i << 5) + srow;
                gload_lds16(wsrc0 + ((size_t)ws << 18) + ((size_t)row << 9) + kc + gs,
                            sm + 8192 + (ws << 13) + (i << 11) + ldso);
            }
        }
        __syncthreads();
#pragma unroll
        for (int kk = 0; kk < 64; kk += 32) {
            const int cu = kk + (lg << 3);
            bf16x8 af[4];
#pragma unroll
            for (int m = 0; m < 4; ++m)
                af[m] = *(const bf16x8*)&Xs[swz64((wm << 6) + (m << 4) + l15, cu)];
#pragma unroll
            for (int ws = 0; ws < 3; ++ws) {
                const unsigned short* Wsb = sm + 8192 + (ws << 13);
                bf16x8 bfr[4];
#pragma unroll
                for (int n = 0; n < 4; ++n)
                    bfr[n] = *(const bf16x8*)&Wsb[swz64((wn << 6) + (n << 4) + l15, cu)];
#pragma unroll
                for (int m = 0; m < 4; ++m)
#pragma unroll
                    for (int n = 0; n < 4; ++n)
                        acc[ws][m][n] = __builtin_amdgcn_mfma_f32_16x16x32_bf16(
                            af[m], bfr[n], acc[ws][m][n], 0, 0, 0);
            }
        }
        __syncthreads();
    }

    // ---- Q/K epilogues: row-major bf16 stores
#pragma unroll
    for (int ws = 0; ws < 2; ++ws) {
        unsigned short* __restrict__ out = ws ? ko : qo;
        const float* __restrict__ bias = ws ? bk : bq;
#pragma unroll
        for (int n = 0; n < 4; ++n) {
            const int col = cbase + (wn << 6) + (n << 4) + l15;
            const float bv_ = bias[col];
#pragma unroll
            for (int m = 0; m < 4; ++m)
#pragma unroll
                for (int j = 0; j < 4; ++j) {
                    const int row = rbase + (wm << 6) + (m << 4) + (lg << 2) + j;
                    out[(size_t)row * DIM + col] = f2b(acc[ws][m][n][j] + bv_);
                }
        }
    }
    // ---- V epilogue: transpose via LDS T[128][129], store Vt3[b][key/32][dv][key%32]
#pragma unroll
    for (int n = 0; n < 4; ++n) {
        const int dv = (wn << 6) + (n << 4) + l15;
        const float bv_ = bv[cbase + dv];
#pragma unroll
        for (int m = 0; m < 4; ++m)
#pragma unroll
            for (int j = 0; j < 4; ++j) {
                const int tok = (wm << 6) + (m << 4) + (lg << 2) + j;
                sm[tok * 129 + dv] = f2b(acc[2][m][n][j] + bv_);
            }
    }
    __syncthreads();
    {
        const int batch = rbase >> 13;
        const int ntok  = rbase & 8191;
        const int dvl0  = tid >> 4;
        const int t16   = (tid & 15) << 3;   // key offset within the 128-tile
#pragma unroll
        for (int p = 0; p < 8; ++p) {
            const int dvl = (p << 4) + dvl0;
            u16x8 v;
#pragma unroll
            for (int j = 0; j < 8; ++j) v[j] = sm[(t16 + j) * 129 + dvl];
            const int key0 = ntok + t16;
            *(u16x8*)&vto[(((size_t)(batch * 256 + (key0 >> 5)) << 9)
                           + (size_t)(cbase + dvl)) * 32 + (key0 & 31)] = v;
        }
    }
}

// ===========================================================================
// Kernel 2: windowed attention. grid = 512 blocks x 512 threads (8 waves).
// Wave w owns q-rows [w*16, w*16+16) of the window; all 256 keys.
// LDS: Kb = 2 x 32KB (K chunks [256][64] swz64; reused as V chunks [512][32]),
//      Pl = 8 x 8KB wave-private P strips [16][256] (slot-XOR swizzled).
// ===========================================================================
__global__ __launch_bounds__(512, 2) void k_attn(
    const unsigned short* __restrict__ q,
    const unsigned short* __restrict__ k,
    const unsigned short* __restrict__ vt3,
    float* __restrict__ out)
{
    __shared__ __align__(16) unsigned short Kb[32768];
    __shared__ __align__(16) unsigned short Pl[32768];

    int bid = (int)blockIdx.x;
    bid = (bid & 7) * 64 + (bid >> 3);    // XCD-chunked: one batch per XCD
    const int b = bid >> 6, w = bid & 63;
    const int tid  = threadIdx.x;
    const int lane = tid & 63, wid = tid >> 6;
    const int l15 = lane & 15, lg = lane >> 4;
    const int kstart = (w - 1) << 7;
    const size_t qrow0 = ((size_t)b << 13) + ((size_t)w << 7);
    const size_t kbase = (size_t)b << 13;

    const int srow = tid >> 3;            // 0..63
    const int s0   = tid & 7;

    // ---------------- phase A: S = Q K^T (per-wave 16 x 256, inner 512) -----
    f32x4 acc[16];
#pragma unroll
    for (int n = 0; n < 16; ++n) acc[n] = (f32x4){0.f, 0.f, 0.f, 0.f};

    auto stageK = [&](int buf, int ds) {
#pragma unroll
        for (int i = 0; i < 4; ++i) {
            const int r = (i << 6) + srow;
            int krow = kstart + r; krow = krow < 0 ? 0 : krow;  // masked anyway
            gload_lds16(k + (kbase + krow) * DIM + (ds << 6) + ((s0 ^ (r & 7)) << 3),
                        Kb + (buf << 14) + (i << 12) + (tid << 3));
        }
    };

    stageK(0, 0);
    stageK(1, 1);
    __syncthreads();
    for (int ds = 0; ds < 8; ++ds) {
        const unsigned short* Kc = Kb + ((ds & 1) << 14);
#pragma unroll
        for (int kk2 = 0; kk2 < 2; ++kk2) {
            const int cu = (kk2 << 5) + (lg << 3);
            const bf16x8 af = *(const bf16x8*)
                &q[(qrow0 + (wid << 4) + l15) * DIM + (ds << 6) + cu];
#pragma unroll
            for (int n = 0; n < 16; ++n) {
                const bf16x8 bf = *(const bf16x8*)&Kc[swz64((n << 4) + l15, cu)];
                acc[n] = __builtin_amdgcn_mfma_f32_16x16x32_bf16(af, bf, acc[n], 0, 0, 0);
            }
        }
        __syncthreads();
        if (ds + 2 < 8) stageK(ds & 1, ds + 2);  // 1-deep pipeline, hidden under next compute
    }

    // ---------------- phase B prologue: stage V chunks 0,1 (Kb free now) ----
    const int c5base = kstart >> 5;       // -4 for w==0
    auto stageV = [&](int buf, int kk) {
        int c5 = c5base + kk; c5 = c5 < 0 ? 0 : c5;  // P==0 for those keys
        const unsigned short* src = vt3 + ((size_t)(b * 256 + c5) << 14);
#pragma unroll
        for (int i = 0; i < 4; ++i)
            gload_lds16(src + (i << 12) + (tid << 3),
                        Kb + (buf << 14) + (i << 12) + (tid << 3));
    };
    stageV(0, 0);
    stageV(1, 1);

    // ---------------- per-wave masked softmax (no cross-wave barriers) ------
    const float scale = 0.04419417382415922f;  // 512^-0.5
    float inv[4];
    unsigned short* Pw = Pl + (wid << 12);     // wave-private [16][256] strip
#pragma unroll
    for (int jj = 0; jj < 4; ++jj) {
        const int r  = (lg << 2) + jj;         // wave-local q row
        const int qr = (wid << 4) + r;         // window q row
        float mx = -3.0e38f;
#pragma unroll
        for (int n = 0; n < 16; ++n) {
            const int c = (n << 4) + l15;
            const bool keep = (c <= qr + 128) && (w > 0 || c >= 128);
            const float s = keep ? acc[n][jj] * scale : -INFINITY;
            acc[n][jj] = s;
            mx = fmaxf(mx, s);
        }
#pragma unroll
        for (int o = 1; o < 16; o <<= 1) mx = fmaxf(mx, __shfl_xor(mx, o));
        float sum = 0.f;
#pragma unroll
        for (int n = 0; n < 16; ++n) {
            const float p = __expf(acc[n][jj] - mx);
            acc[n][jj] = p;
            sum += p;
        }
#pragma unroll
        for (int o = 1; o < 16; o <<= 1) sum += __shfl_xor(sum, o);
        inv[jj] = 1.0f / sum;                  // deferred normalization
#pragma unroll
        for (int n = 0; n < 16; ++n) {
            const int c = (n << 4) + l15;
            Pw[(r << 8) + ((((c >> 3) ^ r) << 3) | (c & 7))] = f2b(acc[n][jj]);
        }
    }
    __syncthreads();   // V chunks 0,1 staged; P strips written (own-wave use only)

    // ---------------- phase B: O = P V (per-wave 16 x 512, inner 256) -------
    f32x4 oacc[32];
#pragma unroll
    for (int n = 0; n < 32; ++n) oacc[n] = (f32x4){0.f, 0.f, 0.f, 0.f};

    for (int kk = 0; kk < 8; ++kk) {
        const unsigned short* Vc = Kb + ((kk & 1) << 14);
        const bf16x8 pa = *(const bf16x8*)
            &Pw[(l15 << 8) + ((((kk << 2) + lg) ^ l15) << 3)];
#pragma unroll
        for (int n = 0; n < 32; ++n) {
            const bf16x8 bv_ = *(const bf16x8*)&Vc[(((n << 4) + l15) << 5) + (lg << 3)];
            oacc[n] = __builtin_amdgcn_mfma_f32_16x16x32_bf16(pa, bv_, oacc[n], 0, 0, 0);
        }
        if (kk < 7) {
            __syncthreads();
            if (kk + 2 < 8) stageV(kk & 1, kk + 2);
        }
    }

    // ---------------- epilogue: normalize and store f32 ---------------------
#pragma unroll
    for (int n = 0; n < 32; ++n) {
        const int dv = (n << 4) + l15;
        float* orow = out + (qrow0 + (wid << 4) + (lg << 2)) * DIM + dv;
#pragma unroll
        for (int jj = 0; jj < 4; ++jj)
            orow[(size_t)jj * DIM] = oacc[n][jj] * inv[jj];
    }
}

// ===========================================================================
extern "C" void kernel_launch(void* const* d_in, const int* in_sizes, int n_in,
                              void* d_out, int out_size, void* d_ws, size_t ws_size,
                              hipStream_t stream) {
    (void)in_sizes; (void)n_in; (void)out_size; (void)ws_size;
    const float* x  = (const float*)d_in[0];
    const float* wq = (const float*)d_in[1];
    const float* bq = (const float*)d_in[2];
    const float* wk = (const float*)d_in[3];
    const float* bk = (const float*)d_in[4];
    const float* wv = (const float*)d_in[5];
    const float* bv = (const float*)d_in[6];
    float* out = (float*)d_out;

    unsigned short* qws  = (unsigned short*)d_ws;
    unsigned short* kws  = qws + WSELEM;
    unsigned short* vtws = kws + WSELEM;

    unsigned short* xbuf = (unsigned short*)d_out;   // consumed before k_attn writes out
    unsigned short* wbuf = xbuf + WSELEM;

    k_cvt<<<2048, 256, 0, stream>>>(x, xbuf, (int)(WSELEM / 8));
    k_cvt<<<128, 256, 0, stream>>>(wq, wbuf, DIM * DIM / 8);
    k_cvt<<<128, 256, 0, stream>>>(wk, wbuf + DIM * DIM, DIM * DIM / 8);
    k_cvt<<<128, 256, 0, stream>>>(wv, wbuf + 2 * DIM * DIM, DIM * DIM / 8);
    k_qkv<<<2048, 256, 0, stream>>>(xbuf, wbuf, bq, bk, bv, qws, kws, vtws);
    k_attn<<<512, 512, 0, stream>>>(qws, kws, vtws, out);
}